// Round 9
// baseline (264.859 us; speedup 1.0000x reference)
//
#include <hip/hip_runtime.h>

typedef __attribute__((ext_vector_type(8))) __bf16 bf16x8;
typedef __attribute__((ext_vector_type(4))) float float4_;
typedef __attribute__((ext_vector_type(16))) float f32x16;
typedef __attribute__((ext_vector_type(4))) unsigned short ushort4_;
typedef __attribute__((ext_vector_type(8))) unsigned short ushort8_;

// ---- 32x32x16 MFMA fragment scheme (all layouts derive from this) ----
// A (32n x 16k):  lane l holds A[n=l&31][k=(l>>5)*8+j], j=0..7
// B (16k x 32pt): lane l holds B[k=(l>>5)*8+j][p=l&31]
// packed tile (512 shorts): elem(n|p, k) at (n&31)*8 + ((k>>3)&1)*256 + (k&7)
//   -> every fragment access is tile_base + lane*16B (coalesced, 2-way-free)
// C/D (HW-verified m74/m101): col=lane&31(=pt), row=(reg&3)+8*(reg>>2)+4*(lane>>5)
// LDS acts: tiles [kt][mt] (kt=k>>4, mt=pt>>5), tile idx = kt*2+mt.
// Weights:  tiles [kt][nt], nt tiles of 32 neurons, NTB tiles per k-step.
// [R8 verified correct @ (512,6): 189us, stall-bound at 24 waves/CU.
//  This rev: no aN + (512,8) -> ~58 unified regs fits 64 cap -> 4 blocks/CU,
//  32 waves/CU, grid 2048 = exactly 2 tail-free rounds. Spill tell=WRITE_SIZE.]

#define OFF_W0T 0        // Kp=48  (KT=3),  NTB=8  (12288)
#define OFF_W1T 12288    // Kp=256 (KT=16), NTB=8  (65536 each x4)
#define OFF_W5T 274432   // Kp=304 (KT=19), NTB=8  (77824)
#define OFF_W6T 352256
#define OFF_W7T 417792   // W7[:,1:257]
#define OFF_WCT 483328   // N=128 -> NTB=4, Kp=256 (32768)
#define BF16_TOTAL 516096
#define WSF_BYTE_OFF (BF16_TOTAL * 2)  // f32: w7sig[256], b7a[256]

// software RNE f32->bf16 (prep kernel only; off critical path)
__device__ __forceinline__ unsigned short f2b(float v) {
  union { float f; unsigned u; } a; a.f = v;
  unsigned r = a.u + 0x7fffu + ((a.u >> 16) & 1u);
  return (unsigned short)(r >> 16);
}

// hardware RNE f32->bf16 via native cast (R5 verified: -12us vs sw f2b)
__device__ __forceinline__ unsigned short f2b_hw(float v) {
  union { __bf16 b; unsigned short u; } a; a.b = (__bf16)v; return a.u;
}

__device__ __forceinline__ ushort4_ pack4(float4_ v) {
  ushort4_ r;
  r.x = f2b_hw(v.x); r.y = f2b_hw(v.y); r.z = f2b_hw(v.z); r.w = f2b_hw(v.w);
  return r;
}

// ---------------- weight prep: coalesced reads, MFMA-tile packed ----------
__global__ __launch_bounds__(256) void prep_kernel(
    const float* __restrict__ W0, const float* __restrict__ W1,
    const float* __restrict__ W2, const float* __restrict__ W3,
    const float* __restrict__ W4, const float* __restrict__ W5,
    const float* __restrict__ W6, const float* __restrict__ W7,
    const float* __restrict__ Wc, const float* __restrict__ b7,
    unsigned short* __restrict__ wsb, float* __restrict__ wsf)
{
  int i = blockIdx.x * 256 + threadIdx.x;
  const float* src; int rs, K, n, k2, ntb; unsigned short* base;
  if (i < 6144)        { n = i & 255; k2 = i >> 8;  src = W0; rs = 256; K = 39;  ntb = 8; base = wsb + OFF_W0T; }
  else if (i < 137216) { int t = i - 6144; int l = t >> 15; t &= 32767;
                         n = t & 255; k2 = t >> 8;
                         src = (l == 0) ? W1 : (l == 1) ? W2 : (l == 2) ? W3 : W4;
                         rs = 256; K = 256; ntb = 8; base = wsb + OFF_W1T + l * 65536; }
  else if (i < 176128) { int t = i - 137216; n = t & 255; k2 = t >> 8; src = W5;     rs = 256; K = 295; ntb = 8; base = wsb + OFF_W5T; }
  else if (i < 208896) { int t = i - 176128; n = t & 255; k2 = t >> 8; src = W6;     rs = 256; K = 256; ntb = 8; base = wsb + OFF_W6T; }
  else if (i < 241664) { int t = i - 208896; n = t & 255; k2 = t >> 8; src = W7 + 1; rs = 257; K = 256; ntb = 8; base = wsb + OFF_W7T; }
  else if (i < 258048) { int t = i - 241664; n = t & 127; k2 = t >> 7; src = Wc;     rs = 128; K = 256; ntb = 4; base = wsb + OFF_WCT; }
  else if (i < 258304) { int k = i - 258048; wsf[k] = W7[k * 257]; return; }
  else if (i < 258560) { int k = i - 258304; wsf[256 + k] = b7[k + 1]; return; }
  else return;
  const int k = k2 * 2;
  const float v0 = (k     < K) ? src[k * rs + n]       : 0.f;
  const float v1 = (k + 1 < K) ? src[(k + 1) * rs + n] : 0.f;
  const int off = ((k >> 4) * ntb + (n >> 5)) * 512
                + (n & 31) * 8 + ((k >> 3) & 1) * 256 + (k & 7);
  const unsigned val = (unsigned)f2b(v0) | ((unsigned)f2b(v1) << 16);
  *(unsigned*)(base + off) = val;
}

// --- one layer, 32x32x16: wave owns nt (32 neurons) x MT m-tiles (pts) ---
// Trunk (MT=2): 8 waves x 8 n-tiles, both m-tiles -> 2 MFMA + 2 LDS b128 +
// 1 weight b128 per K-step. Wc (MT=1): 8 waves = 4 nt x 2 mt.
// No explicit weight prefetch: the K-loop is fully unrolled with no internal
// barriers -> compiler pipelines global loads up to the register budget
// (m131-m140: explicit source prefetch is neutral). Keeps demand ~58 <= 64.
// Zero-padded K (prep + sEmb) -> no edge masking anywhere.
template<int MT, int NTB, int KS1, int KS2, bool RELU>
__device__ __forceinline__ void layer_mm(
    const unsigned short* src1, const unsigned short* src2,
    const unsigned short* __restrict__ wT,
    const float* bias,
    unsigned short* dst, int lane, int wave)
{
  constexpr int KT = KS1 + KS2;
  const int hi = lane >> 5, p = lane & 31;
  const int nt  = (MT == 2) ? wave : (wave >> 1);
  const int mt0 = (MT == 2) ? 0 : (wave & 1);
  const int n0 = nt * 32;
  const unsigned short* wl = wT + nt * 512 + lane * 8;

  f32x16 acc[MT];
  {
    f32x16 a0;
#pragma unroll
    for (int g = 0; g < 4; ++g) {   // acc reg 4g+i holds row 8g+4hi+i
      float4_ bv = *(const float4_*)(bias + n0 + g * 8 + hi * 4);
      a0[4 * g + 0] = bv.x; a0[4 * g + 1] = bv.y;
      a0[4 * g + 2] = bv.z; a0[4 * g + 3] = bv.w;
    }
#pragma unroll
    for (int mt = 0; mt < MT; ++mt) acc[mt] = a0;
  }

#pragma unroll
  for (int ks = 0; ks < KT; ++ks) {
    bf16x8 aC = *(const bf16x8*)(wl + ks * (NTB * 512));
    bf16x8 bfr[MT];
#pragma unroll
    for (int mt = 0; mt < MT; ++mt) {
      const int mtt = mt0 + mt;
      if (ks < KS1)
        bfr[mt] = *(const bf16x8*)(src1 + (ks * 2 + mtt) * 512 + lane * 8);
      else
        bfr[mt] = *(const bf16x8*)(src2 + ((ks - KS1) * 2 + mtt) * 512 + lane * 8);
    }
#pragma unroll
    for (int mt = 0; mt < MT; ++mt)
      acc[mt] = __builtin_amdgcn_mfma_f32_32x32x16_bf16(aC, bfr[mt], acc[mt], 0, 0, 0);
  }

  __syncthreads();   // all compute reads of sAct complete before overwrite
  // store: k_next = n0+8g+4hi+i, pt = mtt*32+p -> 4 consecutive shorts = 8B
#pragma unroll
  for (int mt = 0; mt < MT; ++mt) {
    const int mtt = mt0 + mt;
#pragma unroll
    for (int g = 0; g < 4; ++g) {
      float4_ v = { acc[mt][4 * g + 0], acc[mt][4 * g + 1],
                    acc[mt][4 * g + 2], acc[mt][4 * g + 3] };
      if (RELU) {
        v.x = fmaxf(v.x, 0.f); v.y = fmaxf(v.y, 0.f);
        v.z = fmaxf(v.z, 0.f); v.w = fmaxf(v.w, 0.f);
      }
      const int sidx = (((n0 >> 4) + (g >> 1)) * 2 + mtt) * 512
                     + p * 8 + (g & 1) * 256 + hi * 4;
      *(ushort4_*)(dst + sidx) = pack4(v);
    }
  }
  __syncthreads();   // writes visible before next layer reads
}

// - fused NeRF fwd: 1 ray (64 pts)/block, 8 waves, 32x32x16, 4 blocks/CU -
// (512,8): LDS 39936*4 = 159.7KB <= 160KB; ~58 unified regs <= 64 cap.
// 1024 resident -> 2048 grid = exactly 2 tail-free rounds, 32 waves/CU.
__global__ __launch_bounds__(512, 8) void nerf_kernel(
    const float* __restrict__ pts, const float* __restrict__ dirs,
    const float* __restrict__ b0, const float* __restrict__ b1,
    const float* __restrict__ b2, const float* __restrict__ b3,
    const float* __restrict__ b4, const float* __restrict__ b5,
    const float* __restrict__ b6, const float* __restrict__ b7,
    const float* __restrict__ Wc, const float* __restrict__ bc,
    const float* __restrict__ Wo, const float* __restrict__ bo,
    const unsigned short* __restrict__ wsb, const float* __restrict__ wsf,
    float* __restrict__ out)
{
  __shared__ __align__(16) unsigned short sAct[32 * 512];  // 32 KB (32 tiles)
  __shared__ __align__(16) unsigned short sEmb[6 * 512];   // 6 KB (48k x 64pt)
  __shared__ float s_dvec[27];
  __shared__ float s_biasc[128];

  const int ray = blockIdx.x;
  const int t = threadIdx.x;
  const int lane = t & 63;
  const int wave = t >> 6;

  // xyz harmonic embedding -> sEmb in B-frag tile layout, cols 39..47 = 0
  {
    const int m = t >> 3, s8 = t & 7;          // point 0..63, col group 0..7
    const float* pb = pts + (ray * 64 + m) * 3;
    const float x0 = pb[0], x1 = pb[1], x2 = pb[2];
#pragma unroll
    for (int j = 0; j < 6; ++j) {
      const int cc = s8 * 6 + j;
      float v = 0.f;
      if (cc < 18) {
        const float xx = (cc < 6) ? x0 : (cc < 12) ? x1 : x2;
        v = sinf(xx * (float)(1 << (cc % 6)));
      } else if (cc < 36) {
        const int c2 = cc - 18;
        const float xx = (c2 < 6) ? x0 : (c2 < 12) ? x1 : x2;
        v = cosf(xx * (float)(1 << (c2 % 6)));
      } else if (cc == 36) v = x0;
      else if (cc == 37) v = x1;
      else if (cc == 38) v = x2;
      sEmb[((cc >> 4) * 2 + (m >> 5)) * 512
           + (m & 31) * 8 + ((cc >> 3) & 1) * 256 + (cc & 7)] = f2b_hw(v);
    }
  }
  if (t < 27) {   // direction harmonic embedding (ray-constant)
    const float* db = dirs + ray * 3;
    float v;
    if (t < 12) v = sinf(db[t >> 2] * (float)(1 << (t & 3)));
    else if (t < 24) { const int j2 = t - 12; v = cosf(db[j2 >> 2] * (float)(1 << (j2 & 3))); }
    else v = db[t - 24];
    s_dvec[t] = v;
  }
  __syncthreads();
  if (t < 128) {  // fold dir-embedding part of Wc into per-ray bias
    float s = bc[t];
#pragma unroll
    for (int j = 0; j < 27; ++j) s += s_dvec[j] * Wc[(256 + j) * 128 + t];
    s_biasc[t] = s;
  }
  // s_biasc writes are covered by layer0's internal barriers (read much later)

  // trunk
  layer_mm<2, 8, 0,  3, true >(sAct, sEmb, wsb + OFF_W0T, b0, sAct, lane, wave);
  layer_mm<2, 8, 16, 0, true >(sAct, sEmb, wsb + OFF_W1T,           b1, sAct, lane, wave);
  layer_mm<2, 8, 16, 0, true >(sAct, sEmb, wsb + OFF_W1T +  65536,  b2, sAct, lane, wave);
  layer_mm<2, 8, 16, 0, true >(sAct, sEmb, wsb + OFF_W1T + 131072,  b3, sAct, lane, wave);
  layer_mm<2, 8, 16, 0, true >(sAct, sEmb, wsb + OFF_W1T + 196608,  b4, sAct, lane, wave);
  layer_mm<2, 8, 16, 3, true >(sAct, sEmb, wsb + OFF_W5T, b5, sAct, lane, wave);  // skip concat
  layer_mm<2, 8, 16, 0, true >(sAct, sEmb, wsb + OFF_W6T, b6, sAct, lane, wave);

  // sigma = relu(h6 . W7[:,0] + b7[0]); h6 in sAct (32x32 tile layout)
  {
    const int m = t >> 3, q8 = t & 7;
    float s = 0.f;
#pragma unroll
    for (int i8 = 0; i8 < 4; ++i8) {
      const int kb = q8 * 32 + i8 * 8;
      bf16x8 hv = *(const bf16x8*)(sAct + ((kb >> 4) * 2 + (m >> 5)) * 512
                                       + ((kb >> 3) & 1) * 256 + (m & 31) * 8);
      const float* w = wsf + kb;
#pragma unroll
      for (int j = 0; j < 8; ++j) s += (float)hv[j] * w[j];
    }
    s += __shfl_xor(s, 1); s += __shfl_xor(s, 2); s += __shfl_xor(s, 4);
    if (q8 == 0) out[393216 + ray * 64 + m] = fmaxf(s + b7[0], 0.f);
  }
  // sigma reads precede each thread's L7 compute; L7's internal barrier
  // precedes its writes -> no race.

  layer_mm<2, 8, 16, 0, false>(sAct, sEmb, wsb + OFF_W7T, wsf + 256, sAct, lane, wave);
  // Wc: 128 outputs -> MT=1 (8 waves = 4 nt x 2 mt), per-ray bias
  layer_mm<1, 4, 16, 0, true >(sAct, sEmb, wsb + OFF_WCT, s_biasc, sAct, lane, wave);

  // color = sigmoid(c @ Wo + bo); c = 128 dims in sAct tiles 0..15
  {
    const int m = t >> 3, q8 = t & 7;
    float s0 = 0.f, s1 = 0.f, s2 = 0.f;
#pragma unroll
    for (int i2 = 0; i2 < 2; ++i2) {
      const int kb = q8 * 16 + i2 * 8;
      bf16x8 cv = *(const bf16x8*)(sAct + ((kb >> 4) * 2 + (m >> 5)) * 512
                                       + ((kb >> 3) & 1) * 256 + (m & 31) * 8);
#pragma unroll
      for (int j = 0; j < 8; ++j) {
        const float cc = (float)cv[j];
        const float* w = Wo + (kb + j) * 3;
        s0 += cc * w[0]; s1 += cc * w[1]; s2 += cc * w[2];
      }
    }
    s0 += __shfl_xor(s0, 1); s0 += __shfl_xor(s0, 2); s0 += __shfl_xor(s0, 4);
    s1 += __shfl_xor(s1, 1); s1 += __shfl_xor(s1, 2); s1 += __shfl_xor(s1, 4);
    s2 += __shfl_xor(s2, 1); s2 += __shfl_xor(s2, 2); s2 += __shfl_xor(s2, 4);
    if (q8 == 0) {
      float* oc = out + (ray * 64 + m) * 3;
      oc[0] = 1.f / (1.f + __expf(-(s0 + bo[0])));
      oc[1] = 1.f / (1.f + __expf(-(s1 + bo[1])));
      oc[2] = 1.f / (1.f + __expf(-(s2 + bo[2])));
    }
  }
}

extern "C" void kernel_launch(void* const* d_in, const int* in_sizes, int n_in,
                              void* d_out, int out_size, void* d_ws, size_t ws_size,
                              hipStream_t stream)
{
  const float* pts  = (const float*)d_in[0];
  const float* dirs = (const float*)d_in[1];
  const float* W0 = (const float*)d_in[2];   const float* b0 = (const float*)d_in[3];
  const float* W1 = (const float*)d_in[4];   const float* b1 = (const float*)d_in[5];
  const float* W2 = (const float*)d_in[6];   const float* b2 = (const float*)d_in[7];
  const float* W3 = (const float*)d_in[8];   const float* b3 = (const float*)d_in[9];
  const float* W4 = (const float*)d_in[10];  const float* b4 = (const float*)d_in[11];
  const float* W5 = (const float*)d_in[12];  const float* b5 = (const float*)d_in[13];
  const float* W6 = (const float*)d_in[14];  const float* b6 = (const float*)d_in[15];
  const float* W7 = (const float*)d_in[16];  const float* b7 = (const float*)d_in[17];
  const float* Wc = (const float*)d_in[18];  const float* bc = (const float*)d_in[19];
  const float* Wo = (const float*)d_in[20];  const float* bo = (const float*)d_in[21];

  unsigned short* wsb = (unsigned short*)d_ws;
  float* wsf = (float*)((char*)d_ws + WSF_BYTE_OFF);

  prep_kernel<<<1010, 256, 0, stream>>>(W0, W1, W2, W3, W4, W5, W6, W7, Wc, b7, wsb, wsf);
  nerf_kernel<<<2048, 512, 0, stream>>>(pts, dirs, b0, b1, b2, b3, b4, b5, b6, b7,
                                        Wc, bc, Wo, bo, wsb, wsf, (float*)d_out);
}

// Round 10
// 252.545 us; speedup vs baseline: 1.0488x; 1.0488x over previous
//
#include <hip/hip_runtime.h>

typedef __attribute__((ext_vector_type(8))) __bf16 bf16x8;
typedef __attribute__((ext_vector_type(4))) float float4_;
typedef __attribute__((ext_vector_type(4))) unsigned short ushort4_;
typedef __attribute__((ext_vector_type(8))) unsigned short ushort8_;

// 16x16x32 scheme (R5-proven). Weights packed as MFMA A-fragment tiles of 512
// bf16, order [kt][ntile]. Activations in LDS as B-fragment tiles [kt][mtile].
// elem (n|pt, k) within tile: ((k>>3)&3)*128 + (n&15)*8 + (k&7)
// [R9 lesson: occupancy is NOT the lever (78% occ, same dur). R5's binding
//  pipe is LDS-read: 8 waves re-read the same B-frags -> 98us/CU. This rev:
//  2 rays/block, NT=4, 4 waves/ray -> B-reads per ray HALVED. Reg demand
//  64 acc + ~45 arch = ~109 <= (512,4) cap 128 -> 4 waves/SIMD, no spill.]
#define OFF_W0T 0        // Kp=64  (KT=2),  NTB=16
#define OFF_W1T 16384    // Kp=256 x4,      NTB=16
#define OFF_W2T 81920
#define OFF_W3T 147456
#define OFF_W4T 212992
#define OFF_W5T 278528   // Kp=320 (KT=10), NTB=16
#define OFF_W6T 360448
#define OFF_W7T 425984   // W7[:,1:257]
#define OFF_WCT 491520   // N=128 -> NTB=8, Kp=256
#define BF16_TOTAL 524288
#define WSF_BYTE_OFF (BF16_TOTAL * 2)  // f32: w7sig[256], b7a[256]

#define ACT_T 16384      // shorts per ray act buffer (32 tiles)
#define EMB_T 2592       // shorts per ray emb buffer (64*40 + 32 pad)

// software RNE f32->bf16 (prep kernel only; off critical path)
__device__ __forceinline__ unsigned short f2b(float v) {
  union { float f; unsigned u; } a; a.f = v;
  unsigned r = a.u + 0x7fffu + ((a.u >> 16) & 1u);
  return (unsigned short)(r >> 16);
}

// hardware RNE f32->bf16 via native cast (R5 verified: -12us vs sw f2b)
__device__ __forceinline__ unsigned short f2b_hw(float v) {
  union { __bf16 b; unsigned short u; } a; a.b = (__bf16)v; return a.u;
}

__device__ __forceinline__ bf16x8 bzero() {
  union { ushort8_ u; bf16x8 b; } z;
  ushort8_ t = {0, 0, 0, 0, 0, 0, 0, 0};
  z.u = t;
  return z.b;
}

__device__ __forceinline__ ushort4_ pack4(float4_ v) {
  ushort4_ r;
  r.x = f2b_hw(v.x); r.y = f2b_hw(v.y); r.z = f2b_hw(v.z); r.w = f2b_hw(v.w);
  return r;
}

// ---------------- weight prep: coalesced reads, MFMA-tile packed ----------
__global__ __launch_bounds__(256) void prep_kernel(
    const float* __restrict__ W0, const float* __restrict__ W1,
    const float* __restrict__ W2, const float* __restrict__ W3,
    const float* __restrict__ W4, const float* __restrict__ W5,
    const float* __restrict__ W6, const float* __restrict__ W7,
    const float* __restrict__ Wc, const float* __restrict__ b7,
    unsigned short* __restrict__ wsb, float* __restrict__ wsf)
{
  int i = blockIdx.x * 256 + threadIdx.x;
  const float* src; int rs, K, n, k2, nt16; unsigned short* base;
  if (i < 8192)        { int t = i;          n = t & 255; k2 = t >> 8; src = W0; rs = 256; K = 39;  nt16 = 16; base = wsb + OFF_W0T; }
  else if (i < 139264) { int t = i - 8192;   int l = t >> 15; t &= 32767;
                         n = t & 255; k2 = t >> 8;
                         src = (l == 0) ? W1 : (l == 1) ? W2 : (l == 2) ? W3 : W4;
                         rs = 256; K = 256; nt16 = 16; base = wsb + OFF_W1T + l * 65536; }
  else if (i < 180224) { int t = i - 139264; n = t & 255; k2 = t >> 8; src = W5;     rs = 256; K = 295; nt16 = 16; base = wsb + OFF_W5T; }
  else if (i < 212992) { int t = i - 180224; n = t & 255; k2 = t >> 8; src = W6;     rs = 256; K = 256; nt16 = 16; base = wsb + OFF_W6T; }
  else if (i < 245760) { int t = i - 212992; n = t & 255; k2 = t >> 8; src = W7 + 1; rs = 257; K = 256; nt16 = 16; base = wsb + OFF_W7T; }
  else if (i < 262144) { int t = i - 245760; n = t & 127; k2 = t >> 7; src = Wc;     rs = 128; K = 256; nt16 = 8;  base = wsb + OFF_WCT; }
  else if (i < 262400) { int k = i - 262144; wsf[k] = W7[k * 257]; return; }
  else if (i < 262656) { int k = i - 262400; wsf[256 + k] = b7[k + 1]; return; }
  else return;
  const int k = k2 * 2;
  const float v0 = (k     < K) ? src[k * rs + n]       : 0.f;
  const float v1 = (k + 1 < K) ? src[(k + 1) * rs + n] : 0.f;
  const int off = ((k >> 5) * nt16 + (n >> 4)) * 512
                + ((k >> 3) & 3) * 128 + (n & 15) * 8 + (k & 7);
  const unsigned val = (unsigned)f2b(v0) | ((unsigned)f2b(v1) << 16);
  *(unsigned*)(base + off) = val;
}

// --- one layer: 64 pts (wave's ray) x (NT*16) neurons, swapped MFMA ---
// NT=4 body is R4-proven algebra. No explicit aN prefetch (R8/R9: compiler
// pipelines the unrolled loads within budget). wq = wave&3 (neuron quarter);
// src1/src2/dst are the WAVE'S RAY buffers.
template<int NT, int NTB, int KS1, int KS2, bool RELU>
__device__ __forceinline__ void layer_mm(
    const unsigned short* src1, const unsigned short* src2,
    const unsigned short* __restrict__ wT,
    const float* bias,
    unsigned short* dst, int lane, int wq)
{
  constexpr int KT = KS1 + KS2;
  const int c = lane & 15, q = lane >> 4;
  const int n0 = wq * (NT * 16);
  const unsigned short* wl = wT + (wq * NT) * 512 + lane * 8;

  float4_ acc[4][NT];
#pragma unroll
  for (int ni = 0; ni < NT; ++ni) {
    float4_ bv = *(const float4_*)(bias + n0 + ni * 16 + q * 4);
#pragma unroll
    for (int m4 = 0; m4 < 4; ++m4) acc[m4][ni] = bv;
  }

#pragma unroll
  for (int ks = 0; ks < KT; ++ks) {
    bf16x8 aC[NT];
#pragma unroll
    for (int ni = 0; ni < NT; ++ni)
      aC[ni] = *(const bf16x8*)(wl + (ks * NTB + ni) * 512);
#pragma unroll
    for (int mh = 0; mh < 2; ++mh) {   // 2 chunks of 2 m-tiles
      bf16x8 bfr[2];
#pragma unroll
      for (int m2 = 0; m2 < 2; ++m2) {
        const int mi = mh * 2 + m2;
        if (ks < KS1) {
          bfr[m2] = *(const bf16x8*)(src1 + (ks * 4 + mi) * 512 + lane * 8);
        } else {
          const int kse = ks - KS1;
          bf16x8 ev = *(const bf16x8*)(src2 + (mi * 16 + c) * 40 + kse * 32 + q * 8);
          bfr[m2] = (kse == 0 || q == 0) ? ev : bzero();
        }
      }
#pragma unroll
      for (int ni = 0; ni < NT; ++ni)
#pragma unroll
        for (int m2 = 0; m2 < 2; ++m2)
          acc[mh * 2 + m2][ni] = __builtin_amdgcn_mfma_f32_16x16x32_bf16(
              aC[ni], bfr[m2], acc[mh * 2 + m2][ni], 0, 0, 0);
    }
  }

  __syncthreads();   // all compute reads of sAct complete before overwrite
#pragma unroll
  for (int ni = 0; ni < NT; ++ni) {
    const int base = n0 + ni * 16 + q * 4;
#pragma unroll
    for (int m4 = 0; m4 < 4; ++m4) {
      float4_ v = acc[m4][ni];
      if (RELU) {
        v.x = fmaxf(v.x, 0.f); v.y = fmaxf(v.y, 0.f);
        v.z = fmaxf(v.z, 0.f); v.w = fmaxf(v.w, 0.f);
      }
      const int addr = ((base >> 5) * 4 + m4) * 512
                     + ((base >> 3) & 3) * 128 + c * 8 + (base & 7);
      *(ushort4_*)(dst + addr) = pack4(v);
    }
  }
  __syncthreads();   // writes visible before next layer reads
}

// - fused NeRF fwd: 2 rays (128 pts)/block, 8 waves = 2 rays x 4 n-quarters -
// (512,4): reg demand ~109 <= 128 cap -> 4 waves/SIMD. LDS 77.1KB x 2
// blocks/CU = 154KB <= 160KB. Grid 1024 = 2 tail-free rounds.
__global__ __launch_bounds__(512, 4) void nerf_kernel(
    const float* __restrict__ pts, const float* __restrict__ dirs,
    const float* __restrict__ b0, const float* __restrict__ b1,
    const float* __restrict__ b2, const float* __restrict__ b3,
    const float* __restrict__ b4, const float* __restrict__ b5,
    const float* __restrict__ b6, const float* __restrict__ b7,
    const float* __restrict__ Wc, const float* __restrict__ bc,
    const float* __restrict__ Wo, const float* __restrict__ bo,
    const unsigned short* __restrict__ wsb, const float* __restrict__ wsf,
    float* __restrict__ out)
{
  __shared__ __align__(16) unsigned short sAct[2 * ACT_T];   // 64 KB
  __shared__ __align__(16) unsigned short sEmb[2 * EMB_T];   // 10.1 KB
  __shared__ float s_dvec[2][27];
  __shared__ float s_biasc[2][128];

  const int t = threadIdx.x;
  const int lane = t & 63;
  const int wave = t >> 6;
  const int wray = wave >> 2;      // wave's ray (0/1)
  const int wq   = wave & 3;       // wave's neuron quarter

  // xyz harmonic embedding, 128 pts -> per-ray sEmb rows of 40 cols
  {
    const int m = t >> 2, s4 = t & 3;          // point 0..127, col group 0..3
    const float* pb = pts + ((long)blockIdx.x * 128 + m) * 3;
    const float x0 = pb[0], x1 = pb[1], x2 = pb[2];
    unsigned short* er = sEmb + (m >> 6) * EMB_T + (m & 63) * 40;
#pragma unroll
    for (int j = 0; j < 10; ++j) {
      const int cc = s4 * 10 + j;
      float v = 0.f;
      if (cc < 18) {
        const float xx = (cc < 6) ? x0 : (cc < 12) ? x1 : x2;
        v = sinf(xx * (float)(1 << (cc % 6)));
      } else if (cc < 36) {
        const int c2 = cc - 18;
        const float xx = (c2 < 6) ? x0 : (c2 < 12) ? x1 : x2;
        v = cosf(xx * (float)(1 << (c2 % 6)));
      } else if (cc == 36) v = x0;
      else if (cc == 37) v = x1;
      else if (cc == 38) v = x2;
      er[cc] = f2b_hw(v);
    }
  }
  if (t < 54) {   // direction harmonic embedding, both rays
    const int r = (t >= 27) ? 1 : 0;
    const int j = t - 27 * r;
    const float* db = dirs + (blockIdx.x * 2 + r) * 3;
    float v;
    if (j < 12) v = sinf(db[j >> 2] * (float)(1 << (j & 3)));
    else if (j < 24) { const int j2 = j - 12; v = cosf(db[j2 >> 2] * (float)(1 << (j2 & 3))); }
    else v = db[j - 24];
    s_dvec[r][j] = v;
  }
  __syncthreads();
  if (t < 256) {  // fold dir-embedding part of Wc into per-ray bias
    const int r = t >> 7, cix = t & 127;
    float s = bc[cix];
#pragma unroll
    for (int j = 0; j < 27; ++j) s += s_dvec[r][j] * Wc[(256 + j) * 128 + cix];
    s_biasc[r][cix] = s;
  }
  // s_biasc writes are covered by layer0's internal barriers (read much later)

  unsigned short* rAct = sAct + wray * ACT_T;
  const unsigned short* rEmb = sEmb + wray * EMB_T;

  // trunk
  layer_mm<4, 16, 0, 2, true >(rAct, rEmb, wsb + OFF_W0T, b0, rAct, lane, wq);
  layer_mm<4, 16, 8, 0, true >(rAct, rEmb, wsb + OFF_W1T, b1, rAct, lane, wq);
  layer_mm<4, 16, 8, 0, true >(rAct, rEmb, wsb + OFF_W2T, b2, rAct, lane, wq);
  layer_mm<4, 16, 8, 0, true >(rAct, rEmb, wsb + OFF_W3T, b3, rAct, lane, wq);
  layer_mm<4, 16, 8, 0, true >(rAct, rEmb, wsb + OFF_W4T, b4, rAct, lane, wq);
  layer_mm<4, 16, 8, 2, true >(rAct, rEmb, wsb + OFF_W5T, b5, rAct, lane, wq);  // skip concat
  layer_mm<4, 16, 8, 0, true >(rAct, rEmb, wsb + OFF_W6T, b6, rAct, lane, wq);

  // sigma = relu(h6 . W7[:,0] + b7[0]); 128 pts, 4 threads/pt
  {
    const int m = t >> 2, q4 = t & 3;
    const int lm = m & 63;
    const unsigned short* hA = sAct + (m >> 6) * ACT_T;
    float s = 0.f;
#pragma unroll
    for (int i8 = 0; i8 < 8; ++i8) {
      const int kb = q4 * 64 + i8 * 8;
      bf16x8 hv = *(const bf16x8*)(hA + ((kb >> 5) * 4 + (lm >> 4)) * 512
                                      + ((kb >> 3) & 3) * 128 + (lm & 15) * 8);
      const float* w = wsf + kb;
#pragma unroll
      for (int j = 0; j < 8; ++j) s += (float)hv[j] * w[j];
    }
    s += __shfl_xor(s, 1); s += __shfl_xor(s, 2);
    if (q4 == 0) out[393216 + blockIdx.x * 128 + m] = fmaxf(s + b7[0], 0.f);
  }
  // sigma reads precede each thread's L7 compute; L7's internal barrier
  // precedes its writes -> no race.

  layer_mm<4, 16, 8, 0, false>(rAct, rEmb, wsb + OFF_W7T, wsf + 256, rAct, lane, wq);
  // Wc: 128 outputs -> NT=2 (4 waves x 32 neurons per ray), per-ray bias
  layer_mm<2, 8,  8, 0, true >(rAct, rEmb, wsb + OFF_WCT, s_biasc[wray], rAct, lane, wq);

  // color = sigmoid(c @ Wo + bo); 128 pts, 4 threads/pt, c in tiles 0..15
  {
    const int m = t >> 2, q4 = t & 3;
    const int lm = m & 63;
    const unsigned short* cA = sAct + (m >> 6) * ACT_T;
    float s0 = 0.f, s1 = 0.f, s2 = 0.f;
#pragma unroll
    for (int i2 = 0; i2 < 4; ++i2) {
      const int kb = q4 * 32 + i2 * 8;
      bf16x8 cv = *(const bf16x8*)(cA + ((kb >> 5) * 4 + (lm >> 4)) * 512
                                      + ((kb >> 3) & 3) * 128 + (lm & 15) * 8);
#pragma unroll
      for (int j = 0; j < 8; ++j) {
        const float cc = (float)cv[j];
        const float* w = Wo + (kb + j) * 3;
        s0 += cc * w[0]; s1 += cc * w[1]; s2 += cc * w[2];
      }
    }
    s0 += __shfl_xor(s0, 1); s0 += __shfl_xor(s0, 2);
    s1 += __shfl_xor(s1, 1); s1 += __shfl_xor(s1, 2);
    s2 += __shfl_xor(s2, 1); s2 += __shfl_xor(s2, 2);
    if (q4 == 0) {
      float* oc = out + ((long)blockIdx.x * 128 + m) * 3;
      oc[0] = 1.f / (1.f + __expf(-(s0 + bo[0])));
      oc[1] = 1.f / (1.f + __expf(-(s1 + bo[1])));
      oc[2] = 1.f / (1.f + __expf(-(s2 + bo[2])));
    }
  }
}

extern "C" void kernel_launch(void* const* d_in, const int* in_sizes, int n_in,
                              void* d_out, int out_size, void* d_ws, size_t ws_size,
                              hipStream_t stream)
{
  const float* pts  = (const float*)d_in[0];
  const float* dirs = (const float*)d_in[1];
  const float* W0 = (const float*)d_in[2];   const float* b0 = (const float*)d_in[3];
  const float* W1 = (const float*)d_in[4];   const float* b1 = (const float*)d_in[5];
  const float* W2 = (const float*)d_in[6];   const float* b2 = (const float*)d_in[7];
  const float* W3 = (const float*)d_in[8];   const float* b3 = (const float*)d_in[9];
  const float* W4 = (const float*)d_in[10];  const float* b4 = (const float*)d_in[11];
  const float* W5 = (const float*)d_in[12];  const float* b5 = (const float*)d_in[13];
  const float* W6 = (const float*)d_in[14];  const float* b6 = (const float*)d_in[15];
  const float* W7 = (const float*)d_in[16];  const float* b7 = (const float*)d_in[17];
  const float* Wc = (const float*)d_in[18];  const float* bc = (const float*)d_in[19];
  const float* Wo = (const float*)d_in[20];  const float* bo = (const float*)d_in[21];

  unsigned short* wsb = (unsigned short*)d_ws;
  float* wsf = (float*)((char*)d_ws + WSF_BYTE_OFF);

  prep_kernel<<<1026, 256, 0, stream>>>(W0, W1, W2, W3, W4, W5, W6, W7, Wc, b7, wsb, wsf);
  nerf_kernel<<<1024, 512, 0, stream>>>(pts, dirs, b0, b1, b2, b3, b4, b5, b6, b7,
                                        Wc, bc, Wo, bo, wsb, wsf, (float*)d_out);
}